// Round 1
// baseline (3310.868 us; speedup 1.0000x reference)
//
#include <hip/hip_runtime.h>
#include <hip/hip_bf16.h>

#define M_ROWS 8192      // B*L
#define DM 256           // D_MODEL
#define DI 512           // D_INNER
#define DS 16            // D_STATE
#define DTR 16           // DT_RANK
#define LSEQ 1024

// ---------------------------------------------------------------------------
// Tiled fp32 GEMM:  C[m,n] (+)= alpha * (sum_k A[m,k] * W[n,k] + bias[n])
// W is row-major N x K (so this computes A @ W^T, matching einsum('md,ed->me')).
// ACT: 0 = none, 1 = softplus.  ACCUM: accumulate into C with alpha (from dev ptr).
// ---------------------------------------------------------------------------
template<int ACT, bool ACCUM>
__global__ __launch_bounds__(256)
void gemm_nt(const float* __restrict__ A, int lda,
             const float* __restrict__ W,
             const float* __restrict__ bias,
             const float* __restrict__ alpha_p,
             float* __restrict__ C, int ldc,
             int M, int N, int K)
{
    __shared__ __align__(16) float As[64][17];   // [m][k], padded
    __shared__ __align__(16) float Bs[16][68];   // [k][n], padded

    const int t  = threadIdx.x;
    const int tx = t & 15;        // n direction (0..15)
    const int ty = t >> 4;        // m direction (0..15)
    const int m0 = blockIdx.x * 64;
    const int n0 = blockIdx.y * 64;

    float acc[4][4] = {};

    const int lm = t >> 2;        // 0..63 (row for loads)
    const int kq = t & 3;         // 0..3  (k-quad for loads)

    for (int k0 = 0; k0 < K; k0 += 16) {
        // --- load A tile 64x16 (one float4 per thread, coalesced) ---
        {
            float4 v = *(const float4*)&A[(size_t)(m0 + lm) * lda + k0 + kq * 4];
            As[lm][kq * 4 + 0] = v.x;
            As[lm][kq * 4 + 1] = v.y;
            As[lm][kq * 4 + 2] = v.z;
            As[lm][kq * 4 + 3] = v.w;
        }
        // --- load W tile 64x16 (guard n) ---
        {
            float4 v = make_float4(0.f, 0.f, 0.f, 0.f);
            if (n0 + lm < N)
                v = *(const float4*)&W[(size_t)(n0 + lm) * K + k0 + kq * 4];
            Bs[kq * 4 + 0][lm] = v.x;
            Bs[kq * 4 + 1][lm] = v.y;
            Bs[kq * 4 + 2][lm] = v.z;
            Bs[kq * 4 + 3][lm] = v.w;
        }
        __syncthreads();

        #pragma unroll
        for (int k = 0; k < 16; ++k) {
            float a_[4], b_[4];
            #pragma unroll
            for (int i = 0; i < 4; ++i) a_[i] = As[ty * 4 + i][k];
            float4 bv = *(const float4*)&Bs[k][tx * 4];
            b_[0] = bv.x; b_[1] = bv.y; b_[2] = bv.z; b_[3] = bv.w;
            #pragma unroll
            for (int i = 0; i < 4; ++i)
                #pragma unroll
                for (int j = 0; j < 4; ++j)
                    acc[i][j] += a_[i] * b_[j];
        }
        __syncthreads();
    }

    const float alpha = alpha_p ? *alpha_p : 1.0f;
    #pragma unroll
    for (int i = 0; i < 4; ++i) {
        const int m = m0 + ty * 4 + i;
        #pragma unroll
        for (int j = 0; j < 4; ++j) {
            const int n = n0 + tx * 4 + j;
            if (n < N) {
                float v = acc[i][j];
                if (bias) v += bias[n];
                if (ACT == 1) v = (v > 20.f) ? v : log1pf(__expf(v));
                if (ACCUM) C[(size_t)m * ldc + n] += alpha * v;
                else       C[(size_t)m * ldc + n] = alpha * v;
            }
        }
    }
}

// ---------------------------------------------------------------------------
// LayerNorm over rows of 256: one 64-lane wave per row, 4 elems/lane.
// ---------------------------------------------------------------------------
__global__ __launch_bounds__(64)
void ln_kernel(const float* __restrict__ in, const float* __restrict__ g,
               const float* __restrict__ b, float* __restrict__ out)
{
    const int row = blockIdx.x;
    const int t = threadIdx.x;
    const float* x = in + (size_t)row * DM;

    float v[4];
    float s = 0.f;
    #pragma unroll
    for (int j = 0; j < 4; ++j) { v[j] = x[t + 64 * j]; s += v[j]; }
    #pragma unroll
    for (int m = 1; m < 64; m <<= 1) s += __shfl_xor(s, m, 64);
    const float mu = s * (1.f / DM);

    float s2 = 0.f;
    #pragma unroll
    for (int j = 0; j < 4; ++j) { float d = v[j] - mu; s2 += d * d; }
    #pragma unroll
    for (int m = 1; m < 64; m <<= 1) s2 += __shfl_xor(s2, m, 64);
    const float var = s2 * (1.f / DM);
    const float sc = 1.f / sqrtf(var + 1e-5f);

    #pragma unroll
    for (int j = 0; j < 4; ++j) {
        const int c = t + 64 * j;
        out[(size_t)row * DM + c] = (v[j] - mu) * sc * g[c] + b[c];
    }
}

// ---------------------------------------------------------------------------
// Causal depthwise conv (width 4) + SiLU.  xi = xz[:, :512].
// ---------------------------------------------------------------------------
__global__ __launch_bounds__(256)
void conv_silu_kernel(const float* __restrict__ xz, const float* __restrict__ cw,
                      const float* __restrict__ cb, float* __restrict__ xc)
{
    const int idx = blockIdx.x * 256 + threadIdx.x;  // over 8192*512
    const int d = idx & (DI - 1);
    const int m = idx >> 9;
    const int l = m & (LSEQ - 1);

    float acc = cb[d];
    #pragma unroll
    for (int k = 0; k < 4; ++k) {
        const int ll = l + k - 3;
        if (ll >= 0)
            acc += xz[(size_t)(m + k - 3) * 1024 + d] * cw[d * 4 + k];
    }
    const float sg = 1.f / (1.f + __expf(-acc));
    xc[idx] = acc * sg;
}

// ---------------------------------------------------------------------------
// Selective scan: 4 lanes per (b,d) channel, 4 states per lane.
// Fuses: y = (scan_out + u*D) * silu(z)  ->  yg
// ---------------------------------------------------------------------------
__global__ __launch_bounds__(64)
void scan_kernel(const float* __restrict__ delta,
                 const float* __restrict__ xc,
                 const float* __restrict__ dbc,
                 const float* __restrict__ xz,
                 const float* __restrict__ A_log,
                 const float* __restrict__ Dp,
                 float* __restrict__ yg)
{
    const int gid  = blockIdx.x * 64 + threadIdx.x;  // 0 .. 16383
    const int q    = gid & 3;
    const int pair = gid >> 2;          // (b,d) index
    const int d    = pair & (DI - 1);
    const int b    = pair >> 9;
    const int n0   = q * 4;

    const float a0 = -__expf(A_log[d * DS + n0 + 0]);
    const float a1 = -__expf(A_log[d * DS + n0 + 1]);
    const float a2 = -__expf(A_log[d * DS + n0 + 2]);
    const float a3 = -__expf(A_log[d * DS + n0 + 3]);
    const float Dv = Dp[d];

    float h0 = 0.f, h1 = 0.f, h2 = 0.f, h3 = 0.f;
    const size_t mbase = (size_t)b * LSEQ;

    for (int l = 0; l < LSEQ; ++l) {
        const size_t m = mbase + l;
        const float dt = delta[m * DI + d];
        const float u  = xc[m * DI + d];
        const float* bc = dbc + m * 48 + DTR + n0;
        const float4 Bv = *(const float4*)(bc);
        const float4 Cv = *(const float4*)(bc + DS);

        const float du = dt * u;
        h0 = h0 * __expf(dt * a0) + du * Bv.x;
        h1 = h1 * __expf(dt * a1) + du * Bv.y;
        h2 = h2 * __expf(dt * a2) + du * Bv.z;
        h3 = h3 * __expf(dt * a3) + du * Bv.w;

        float y = h0 * Cv.x + h1 * Cv.y + h2 * Cv.z + h3 * Cv.w;
        y += __shfl_xor(y, 1, 64);
        y += __shfl_xor(y, 2, 64);

        if (q == 0) {
            const float z = xz[m * 1024 + DI + d];
            const float g = z / (1.f + __expf(-z));
            yg[m * DI + d] = (y + u * Dv) * g;
        }
    }
}

// ---------------------------------------------------------------------------
extern "C" void kernel_launch(void* const* d_in, const int* in_sizes, int n_in,
                              void* d_out, int out_size, void* d_ws, size_t ws_size,
                              hipStream_t stream) {
    const float* x          = (const float*)d_in[0];
    const float* proj_in_w  = (const float*)d_in[1];
    const float* proj_in_b  = (const float*)d_in[2];
    const float* ln_gamma   = (const float*)d_in[3];
    const float* ln_beta    = (const float*)d_in[4];
    const float* in_proj_w  = (const float*)d_in[5];
    const float* conv_w     = (const float*)d_in[6];
    const float* conv_b     = (const float*)d_in[7];
    const float* x_proj_w   = (const float*)d_in[8];
    const float* dt_proj_w  = (const float*)d_in[9];
    const float* dt_proj_b  = (const float*)d_in[10];
    const float* A_log      = (const float*)d_in[11];
    const float* Dvec       = (const float*)d_in[12];
    const float* out_proj_w = (const float*)d_in[13];
    const float* res_scale  = (const float*)d_in[14];
    const float* out_gamma  = (const float*)d_in[15];
    const float* out_beta   = (const float*)d_in[16];

    float* ws     = (float*)d_ws;
    float* h_buf  = ws;                                  // 8192*256
    float* ln_buf = h_buf  + (size_t)M_ROWS * DM;        // 8192*256
    float* xz     = ln_buf + (size_t)M_ROWS * DM;        // 8192*1024
    float* xc     = xz     + (size_t)M_ROWS * 1024;      // 8192*512
    float* delta  = xc     + (size_t)M_ROWS * DI;        // 8192*512
    float* dbc    = delta  + (size_t)M_ROWS * DI;        // 8192*48
    float* yg     = dbc    + (size_t)M_ROWS * 48;        // 8192*512

    // h = x @ proj_in_w^T + proj_in_b   (M=8192, N=256, K=80)
    gemm_nt<0, false><<<dim3(128, 4), 256, 0, stream>>>(
        x, 80, proj_in_w, proj_in_b, nullptr, h_buf, DM, M_ROWS, DM, 80);

    for (int i = 0; i < 4; ++i) {
        const float* in_w  = in_proj_w  + (size_t)i * 2 * DI * DM;
        const float* cw    = conv_w     + (size_t)i * DI * 4;
        const float* cb    = conv_b     + (size_t)i * DI;
        const float* xw    = x_proj_w   + (size_t)i * 48 * DI;
        const float* dtw   = dt_proj_w  + (size_t)i * DI * DTR;
        const float* dtb   = dt_proj_b  + (size_t)i * DI;
        const float* Al    = A_log      + (size_t)i * DI * DS;
        const float* Dl    = Dvec       + (size_t)i * DI;
        const float* ow    = out_proj_w + (size_t)i * DM * DI;

        ln_kernel<<<M_ROWS, 64, 0, stream>>>(h_buf, ln_gamma + i * DM,
                                             ln_beta + i * DM, ln_buf);
        // xz = ln @ in_w^T   (N=1024, K=256)
        gemm_nt<0, false><<<dim3(128, 16), 256, 0, stream>>>(
            ln_buf, DM, in_w, nullptr, nullptr, xz, 1024, M_ROWS, 1024, DM);
        // conv + silu
        conv_silu_kernel<<<(M_ROWS * DI) / 256, 256, 0, stream>>>(xz, cw, cb, xc);
        // dbc = xc @ xw^T    (N=48, K=512)
        gemm_nt<0, false><<<dim3(128, 1), 256, 0, stream>>>(
            xc, DI, xw, nullptr, nullptr, dbc, 48, M_ROWS, 48, DI);
        // delta = softplus(dbc[:, :16] @ dtw^T + dtb)   (N=512, K=16)
        gemm_nt<1, false><<<dim3(128, 8), 256, 0, stream>>>(
            dbc, 48, dtw, dtb, nullptr, delta, DI, M_ROWS, DI, DTR);
        // selective scan + gating
        scan_kernel<<<256, 64, 0, stream>>>(delta, xc, dbc, xz, Al, Dl, yg);
        // h += res_scale * (yg @ ow^T)   (N=256, K=512)
        gemm_nt<0, true><<<dim3(128, 4), 256, 0, stream>>>(
            yg, DI, ow, nullptr, res_scale, h_buf, DM, M_ROWS, DM, DI);
    }

    ln_kernel<<<M_ROWS, 64, 0, stream>>>(h_buf, out_gamma, out_beta, (float*)d_out);
}

// Round 2
// 967.890 us; speedup vs baseline: 3.4207x; 3.4207x over previous
//
#include <hip/hip_runtime.h>
#include <hip/hip_bf16.h>

#define M_ROWS 8192      // B*L
#define DM 256           // D_MODEL
#define DI 512           // D_INNER
#define DS 16            // D_STATE
#define DTR 16           // DT_RANK
#define LSEQ 1024
#define NC 32            // chunks per sequence
#define CT 32            // chunk length (NC*CT == LSEQ)

// ---------------------------------------------------------------------------
// Tiled fp32 GEMM:  C[m,n] (+)= alpha * (sum_k A[m,k] * W[n,k] + bias[n])
// ---------------------------------------------------------------------------
template<int ACT, bool ACCUM>
__global__ __launch_bounds__(256)
void gemm_nt(const float* __restrict__ A, int lda,
             const float* __restrict__ W,
             const float* __restrict__ bias,
             const float* __restrict__ alpha_p,
             float* __restrict__ C, int ldc,
             int M, int N, int K)
{
    __shared__ __align__(16) float As[64][17];
    __shared__ __align__(16) float Bs[16][68];

    const int t  = threadIdx.x;
    const int tx = t & 15;
    const int ty = t >> 4;
    const int m0 = blockIdx.x * 64;
    const int n0 = blockIdx.y * 64;

    float acc[4][4] = {};

    const int lm = t >> 2;
    const int kq = t & 3;

    for (int k0 = 0; k0 < K; k0 += 16) {
        {
            float4 v = *(const float4*)&A[(size_t)(m0 + lm) * lda + k0 + kq * 4];
            As[lm][kq * 4 + 0] = v.x;
            As[lm][kq * 4 + 1] = v.y;
            As[lm][kq * 4 + 2] = v.z;
            As[lm][kq * 4 + 3] = v.w;
        }
        {
            float4 v = make_float4(0.f, 0.f, 0.f, 0.f);
            if (n0 + lm < N)
                v = *(const float4*)&W[(size_t)(n0 + lm) * K + k0 + kq * 4];
            Bs[kq * 4 + 0][lm] = v.x;
            Bs[kq * 4 + 1][lm] = v.y;
            Bs[kq * 4 + 2][lm] = v.z;
            Bs[kq * 4 + 3][lm] = v.w;
        }
        __syncthreads();

        #pragma unroll
        for (int k = 0; k < 16; ++k) {
            float a_[4], b_[4];
            #pragma unroll
            for (int i = 0; i < 4; ++i) a_[i] = As[ty * 4 + i][k];
            float4 bv = *(const float4*)&Bs[k][tx * 4];
            b_[0] = bv.x; b_[1] = bv.y; b_[2] = bv.z; b_[3] = bv.w;
            #pragma unroll
            for (int i = 0; i < 4; ++i)
                #pragma unroll
                for (int j = 0; j < 4; ++j)
                    acc[i][j] += a_[i] * b_[j];
        }
        __syncthreads();
    }

    const float alpha = alpha_p ? *alpha_p : 1.0f;
    #pragma unroll
    for (int i = 0; i < 4; ++i) {
        const int m = m0 + ty * 4 + i;
        #pragma unroll
        for (int j = 0; j < 4; ++j) {
            const int n = n0 + tx * 4 + j;
            if (n < N) {
                float v = acc[i][j];
                if (bias) v += bias[n];
                if (ACT == 1) v = (v > 20.f) ? v : log1pf(__expf(v));
                if (ACCUM) C[(size_t)m * ldc + n] += alpha * v;
                else       C[(size_t)m * ldc + n] = alpha * v;
            }
        }
    }
}

// ---------------------------------------------------------------------------
// LayerNorm over rows of 256: one 64-lane wave per row.
// ---------------------------------------------------------------------------
__global__ __launch_bounds__(64)
void ln_kernel(const float* __restrict__ in, const float* __restrict__ g,
               const float* __restrict__ b, float* __restrict__ out)
{
    const int row = blockIdx.x;
    const int t = threadIdx.x;
    const float* x = in + (size_t)row * DM;

    float v[4];
    float s = 0.f;
    #pragma unroll
    for (int j = 0; j < 4; ++j) { v[j] = x[t + 64 * j]; s += v[j]; }
    #pragma unroll
    for (int m = 1; m < 64; m <<= 1) s += __shfl_xor(s, m, 64);
    const float mu = s * (1.f / DM);

    float s2 = 0.f;
    #pragma unroll
    for (int j = 0; j < 4; ++j) { float d = v[j] - mu; s2 += d * d; }
    #pragma unroll
    for (int m = 1; m < 64; m <<= 1) s2 += __shfl_xor(s2, m, 64);
    const float var = s2 * (1.f / DM);
    const float sc = 1.f / sqrtf(var + 1e-5f);

    #pragma unroll
    for (int j = 0; j < 4; ++j) {
        const int c = t + 64 * j;
        out[(size_t)row * DM + c] = (v[j] - mu) * sc * g[c] + b[c];
    }
}

// ---------------------------------------------------------------------------
// Causal depthwise conv (width 4) + SiLU.
// ---------------------------------------------------------------------------
__global__ __launch_bounds__(256)
void conv_silu_kernel(const float* __restrict__ xz, const float* __restrict__ cw,
                      const float* __restrict__ cb, float* __restrict__ xc)
{
    const int idx = blockIdx.x * 256 + threadIdx.x;
    const int d = idx & (DI - 1);
    const int m = idx >> 9;
    const int l = m & (LSEQ - 1);

    float acc = cb[d];
    #pragma unroll
    for (int k = 0; k < 4; ++k) {
        const int ll = l + k - 3;
        if (ll >= 0)
            acc += xz[(size_t)(m + k - 3) * 1024 + d] * cw[d * 4 + k];
    }
    const float sg = 1.f / (1.f + __expf(-acc));
    xc[idx] = acc * sg;
}

// ---------------------------------------------------------------------------
// Chunked parallel selective scan.
// pass1: per (b,chunk,d) local scan (h0=0), store final S[16] and sum(dt).
// pass2: per (b,d,n) combine chunks: entry states H_c (in-place over S).
// pass3: per (b,chunk,d) re-scan from H_c, fused y-dot + D + SiLU(z) gate.
// ---------------------------------------------------------------------------
__global__ __launch_bounds__(256)
void scan_part1(const float* __restrict__ delta, const float* __restrict__ xc,
                const float* __restrict__ dbc, const float* __restrict__ A_log,
                float* __restrict__ S, float* __restrict__ Dsum)
{
    const int blk = blockIdx.x;            // (b*NC + c)*2 + half
    const int bc  = blk >> 1;              // b*NC + c
    const int d   = ((blk & 1) << 8) + threadIdx.x;
    const int b   = bc >> 5;
    const int c   = bc & (NC - 1);

    float a[16], h[16];
    #pragma unroll
    for (int n = 0; n < 16; ++n) {
        a[n] = -__expf(A_log[d * 16 + n]);
        h[n] = 0.f;
    }
    float dsum = 0.f;

    const int m0 = b * LSEQ + c * CT;
    for (int t = 0; t < CT; ++t) {
        const size_t m = (size_t)(m0 + t);
        const float dt = delta[m * DI + d];
        const float u  = xc[m * DI + d];
        const float du = dt * u;
        dsum += dt;
        const float* Bp = dbc + m * 48 + DTR;   // wave-uniform address
        #pragma unroll
        for (int n = 0; n < 16; ++n)
            h[n] = h[n] * __expf(dt * a[n]) + du * Bp[n];
    }
    float* Sp = S + ((size_t)bc * DI + d) * 16;
    #pragma unroll
    for (int n = 0; n < 16; ++n) Sp[n] = h[n];
    Dsum[(size_t)bc * DI + d] = dsum;
}

__global__ __launch_bounds__(256)
void scan_part2(const float* __restrict__ A_log, const float* __restrict__ Dsum,
                float* __restrict__ S /* in: local finals, out: entry states */)
{
    const int gid = blockIdx.x * 256 + threadIdx.x;  // (b*DI+d)*16+n
    const int n = gid & 15;
    const int d = (gid >> 4) & (DI - 1);
    const int b = gid >> 13;

    const float a = -__expf(A_log[d * 16 + n]);
    float h = 0.f;
    for (int c = 0; c < NC; ++c) {
        const size_t bcd = (size_t)(b * NC + c) * DI + d;
        const size_t idx = bcd * 16 + n;
        const float s = S[idx];
        S[idx] = h;                               // entry state for chunk c
        h = __expf(a * Dsum[bcd]) * h + s;        // exit state of chunk c
    }
}

__global__ __launch_bounds__(256)
void scan_part3(const float* __restrict__ delta, const float* __restrict__ xc,
                const float* __restrict__ dbc, const float* __restrict__ xz,
                const float* __restrict__ A_log, const float* __restrict__ Dp,
                const float* __restrict__ H, float* __restrict__ yg)
{
    const int blk = blockIdx.x;
    const int bc  = blk >> 1;
    const int d   = ((blk & 1) << 8) + threadIdx.x;
    const int b   = bc >> 5;
    const int c   = bc & (NC - 1);

    float a[16], h[16];
    const float* Hp = H + ((size_t)bc * DI + d) * 16;
    #pragma unroll
    for (int n = 0; n < 16; ++n) {
        a[n] = -__expf(A_log[d * 16 + n]);
        h[n] = Hp[n];
    }
    const float Dv = Dp[d];

    const int m0 = b * LSEQ + c * CT;
    for (int t = 0; t < CT; ++t) {
        const size_t m = (size_t)(m0 + t);
        const float dt = delta[m * DI + d];
        const float u  = xc[m * DI + d];
        const float du = dt * u;
        const float* Bp = dbc + m * 48 + DTR;   // wave-uniform
        const float* Cp = Bp + DS;              // wave-uniform
        float y = 0.f;
        #pragma unroll
        for (int n = 0; n < 16; ++n) {
            h[n] = h[n] * __expf(dt * a[n]) + du * Bp[n];
            y += h[n] * Cp[n];
        }
        const float z = xz[m * 1024 + DI + d];
        const float g = z / (1.f + __expf(-z));
        yg[m * DI + d] = (y + u * Dv) * g;
    }
}

// ---------------------------------------------------------------------------
extern "C" void kernel_launch(void* const* d_in, const int* in_sizes, int n_in,
                              void* d_out, int out_size, void* d_ws, size_t ws_size,
                              hipStream_t stream) {
    const float* x          = (const float*)d_in[0];
    const float* proj_in_w  = (const float*)d_in[1];
    const float* proj_in_b  = (const float*)d_in[2];
    const float* ln_gamma   = (const float*)d_in[3];
    const float* ln_beta    = (const float*)d_in[4];
    const float* in_proj_w  = (const float*)d_in[5];
    const float* conv_w     = (const float*)d_in[6];
    const float* conv_b     = (const float*)d_in[7];
    const float* x_proj_w   = (const float*)d_in[8];
    const float* dt_proj_w  = (const float*)d_in[9];
    const float* dt_proj_b  = (const float*)d_in[10];
    const float* A_log      = (const float*)d_in[11];
    const float* Dvec       = (const float*)d_in[12];
    const float* out_proj_w = (const float*)d_in[13];
    const float* res_scale  = (const float*)d_in[14];
    const float* out_gamma  = (const float*)d_in[15];
    const float* out_beta   = (const float*)d_in[16];

    float* ws     = (float*)d_ws;
    float* h_buf  = ws;                                  // 8192*256
    float* ln_buf = h_buf  + (size_t)M_ROWS * DM;        // 8192*256
    float* xz     = ln_buf + (size_t)M_ROWS * DM;        // 8192*1024
    float* xc     = xz     + (size_t)M_ROWS * 1024;      // 8192*512
    float* delta  = xc     + (size_t)M_ROWS * DI;        // 8192*512
    float* dbc    = delta  + (size_t)M_ROWS * DI;        // 8192*48
    float* yg     = dbc    + (size_t)M_ROWS * 48;        // 8192*512
    float* Sbuf   = yg     + (size_t)M_ROWS * DI;        // 8*NC*512*16 = 2M
    float* Dsum   = Sbuf   + (size_t)8 * NC * DI * 16;   // 8*NC*512

    // h = x @ proj_in_w^T + proj_in_b
    gemm_nt<0, false><<<dim3(128, 4), 256, 0, stream>>>(
        x, 80, proj_in_w, proj_in_b, nullptr, h_buf, DM, M_ROWS, DM, 80);

    for (int i = 0; i < 4; ++i) {
        const float* in_w  = in_proj_w  + (size_t)i * 2 * DI * DM;
        const float* cw    = conv_w     + (size_t)i * DI * 4;
        const float* cb    = conv_b     + (size_t)i * DI;
        const float* xw    = x_proj_w   + (size_t)i * 48 * DI;
        const float* dtw   = dt_proj_w  + (size_t)i * DI * DTR;
        const float* dtb   = dt_proj_b  + (size_t)i * DI;
        const float* Al    = A_log      + (size_t)i * DI * DS;
        const float* Dl    = Dvec       + (size_t)i * DI;
        const float* ow    = out_proj_w + (size_t)i * DM * DI;

        ln_kernel<<<M_ROWS, 64, 0, stream>>>(h_buf, ln_gamma + i * DM,
                                             ln_beta + i * DM, ln_buf);
        gemm_nt<0, false><<<dim3(128, 16), 256, 0, stream>>>(
            ln_buf, DM, in_w, nullptr, nullptr, xz, 1024, M_ROWS, 1024, DM);
        conv_silu_kernel<<<(M_ROWS * DI) / 256, 256, 0, stream>>>(xz, cw, cb, xc);
        gemm_nt<0, false><<<dim3(128, 1), 256, 0, stream>>>(
            xc, DI, xw, nullptr, nullptr, dbc, 48, M_ROWS, 48, DI);
        gemm_nt<1, false><<<dim3(128, 8), 256, 0, stream>>>(
            dbc, 48, dtw, dtb, nullptr, delta, DI, M_ROWS, DI, DTR);

        // chunked parallel scan
        scan_part1<<<8 * NC * 2, 256, 0, stream>>>(delta, xc, dbc, Al, Sbuf, Dsum);
        scan_part2<<<(8 * DI * 16) / 256, 256, 0, stream>>>(Al, Dsum, Sbuf);
        scan_part3<<<8 * NC * 2, 256, 0, stream>>>(delta, xc, dbc, xz, Al, Dl,
                                                   Sbuf, yg);

        gemm_nt<0, true><<<dim3(128, 4), 256, 0, stream>>>(
            yg, DI, ow, nullptr, res_scale, h_buf, DM, M_ROWS, DM, DI);
    }

    ln_kernel<<<M_ROWS, 64, 0, stream>>>(h_buf, out_gamma, out_beta, (float*)d_out);
}

// Round 3
// 724.703 us; speedup vs baseline: 4.5686x; 1.3356x over previous
//
#include <hip/hip_runtime.h>
#include <hip/hip_bf16.h>

#define M_ROWS 8192      // B*L
#define DM 256           // D_MODEL
#define DI 512           // D_INNER
#define DS 16            // D_STATE
#define DTR 16           // DT_RANK
#define LSEQ 1024
#define NC 32            // chunks per sequence
#define CT 32            // chunk length

typedef __bf16 bf16x8 __attribute__((ext_vector_type(8)));
typedef float  f32x4  __attribute__((ext_vector_type(4)));

__device__ __forceinline__ bf16x8 ld8(const __hip_bfloat16* p) {
    uint4 u = *(const uint4*)p;
    return __builtin_bit_cast(bf16x8, u);
}

// ---------------------------------------------------------------------------
// bf16 MFMA GEMM:  C[m,n] (+)= alpha * sum_k A[m,k] * W[n,k]
// A: M x K bf16 row-major.  W: N x K bf16 row-major.  C: M x N fp32.
// Block: 256 thr = 4 waves stacked in M. Per-wave tile 32(M) x 64(N).
// Block tile 128 x 64. No LDS; fragments loaded straight from global (L1/L2).
// ---------------------------------------------------------------------------
template<bool ACCUM>
__global__ __launch_bounds__(256)
void gemm_bt_mfma(const __hip_bfloat16* __restrict__ A,
                  const __hip_bfloat16* __restrict__ W,
                  const float* __restrict__ alpha_p,
                  float* __restrict__ C,
                  int M, int N, int K)
{
    const int w  = threadIdx.x >> 6;   // wave 0..3
    const int l  = threadIdx.x & 63;
    const int lr = l & 15;             // fragment row/col index
    const int kb = l >> 4;             // k-block 0..3
    const int m0 = blockIdx.x * 128 + w * 32;
    const int n0 = blockIdx.y * 64;

    f32x4 acc[2][4];
    #pragma unroll
    for (int mi = 0; mi < 2; ++mi)
        #pragma unroll
        for (int ni = 0; ni < 4; ++ni)
            acc[mi][ni] = (f32x4){0.f, 0.f, 0.f, 0.f};

    const __hip_bfloat16* pA = A + (size_t)(m0 + lr) * K + kb * 8;
    const __hip_bfloat16* pW = W + (size_t)(n0 + lr) * K + kb * 8;
    const size_t sK16 = (size_t)16 * K;

    #pragma unroll 2
    for (int k0 = 0; k0 < K; k0 += 32) {
        bf16x8 a0 = ld8(pA + k0);
        bf16x8 a1 = ld8(pA + sK16 + k0);
        bf16x8 b0 = ld8(pW + k0);
        bf16x8 b1 = ld8(pW + sK16 + k0);
        bf16x8 b2 = ld8(pW + 2 * sK16 + k0);
        bf16x8 b3 = ld8(pW + 3 * sK16 + k0);

        acc[0][0] = __builtin_amdgcn_mfma_f32_16x16x32_bf16(a0, b0, acc[0][0], 0, 0, 0);
        acc[1][0] = __builtin_amdgcn_mfma_f32_16x16x32_bf16(a1, b0, acc[1][0], 0, 0, 0);
        acc[0][1] = __builtin_amdgcn_mfma_f32_16x16x32_bf16(a0, b1, acc[0][1], 0, 0, 0);
        acc[1][1] = __builtin_amdgcn_mfma_f32_16x16x32_bf16(a1, b1, acc[1][1], 0, 0, 0);
        acc[0][2] = __builtin_amdgcn_mfma_f32_16x16x32_bf16(a0, b2, acc[0][2], 0, 0, 0);
        acc[1][2] = __builtin_amdgcn_mfma_f32_16x16x32_bf16(a1, b2, acc[1][2], 0, 0, 0);
        acc[0][3] = __builtin_amdgcn_mfma_f32_16x16x32_bf16(a0, b3, acc[0][3], 0, 0, 0);
        acc[1][3] = __builtin_amdgcn_mfma_f32_16x16x32_bf16(a1, b3, acc[1][3], 0, 0, 0);
    }

    const float alpha = alpha_p ? alpha_p[0] : 1.0f;
    #pragma unroll
    for (int mi = 0; mi < 2; ++mi) {
        #pragma unroll
        for (int ni = 0; ni < 4; ++ni) {
            #pragma unroll
            for (int r = 0; r < 4; ++r) {
                const int row = m0 + mi * 16 + kb * 4 + r;
                const int col = n0 + ni * 16 + lr;
                const size_t idx = (size_t)row * N + col;
                if (ACCUM) C[idx] += alpha * acc[mi][ni][r];
                else       C[idx] = acc[mi][ni][r];
            }
        }
    }
}

// ---------------------------------------------------------------------------
// fp32 tiled GEMM (kept for proj_in / x_proj / dt_proj):
// C[m,n] (+)= alpha * (sum_k A[m,k]*W[n,k] + bias[n])
// ---------------------------------------------------------------------------
template<int ACT, bool ACCUM>
__global__ __launch_bounds__(256)
void gemm_nt(const float* __restrict__ A, int lda,
             const float* __restrict__ W,
             const float* __restrict__ bias,
             const float* __restrict__ alpha_p,
             float* __restrict__ C, int ldc,
             int M, int N, int K)
{
    __shared__ __align__(16) float As[64][17];
    __shared__ __align__(16) float Bs[16][68];

    const int t  = threadIdx.x;
    const int tx = t & 15;
    const int ty = t >> 4;
    const int m0 = blockIdx.x * 64;
    const int n0 = blockIdx.y * 64;

    float acc[4][4] = {};

    const int lm = t >> 2;
    const int kq = t & 3;

    for (int k0 = 0; k0 < K; k0 += 16) {
        {
            float4 v = *(const float4*)&A[(size_t)(m0 + lm) * lda + k0 + kq * 4];
            As[lm][kq * 4 + 0] = v.x;
            As[lm][kq * 4 + 1] = v.y;
            As[lm][kq * 4 + 2] = v.z;
            As[lm][kq * 4 + 3] = v.w;
        }
        {
            float4 v = make_float4(0.f, 0.f, 0.f, 0.f);
            if (n0 + lm < N)
                v = *(const float4*)&W[(size_t)(n0 + lm) * K + k0 + kq * 4];
            Bs[kq * 4 + 0][lm] = v.x;
            Bs[kq * 4 + 1][lm] = v.y;
            Bs[kq * 4 + 2][lm] = v.z;
            Bs[kq * 4 + 3][lm] = v.w;
        }
        __syncthreads();

        #pragma unroll
        for (int k = 0; k < 16; ++k) {
            float a_[4], b_[4];
            #pragma unroll
            for (int i = 0; i < 4; ++i) a_[i] = As[ty * 4 + i][k];
            float4 bv = *(const float4*)&Bs[k][tx * 4];
            b_[0] = bv.x; b_[1] = bv.y; b_[2] = bv.z; b_[3] = bv.w;
            #pragma unroll
            for (int i = 0; i < 4; ++i)
                #pragma unroll
                for (int j = 0; j < 4; ++j)
                    acc[i][j] += a_[i] * b_[j];
        }
        __syncthreads();
    }

    const float alpha = alpha_p ? *alpha_p : 1.0f;
    #pragma unroll
    for (int i = 0; i < 4; ++i) {
        const int m = m0 + ty * 4 + i;
        #pragma unroll
        for (int j = 0; j < 4; ++j) {
            const int n = n0 + tx * 4 + j;
            if (n < N) {
                float v = acc[i][j];
                if (bias) v += bias[n];
                if (ACT == 1) v = (v > 20.f) ? v : log1pf(__expf(v));
                if (ACCUM) C[(size_t)m * ldc + n] += alpha * v;
                else       C[(size_t)m * ldc + n] = alpha * v;
            }
        }
    }
}

// ---------------------------------------------------------------------------
// fp32 -> bf16 conversion (8 elems/thread). n must be a multiple of 8.
// ---------------------------------------------------------------------------
__global__ __launch_bounds__(256)
void cvt_bf16_kernel(const float* __restrict__ in, __hip_bfloat16* __restrict__ out,
                     int n)
{
    const int i = (blockIdx.x * 256 + threadIdx.x) * 8;
    if (i >= n) return;
    float4 a = *(const float4*)(in + i);
    float4 b = *(const float4*)(in + i + 4);
    union { __hip_bfloat16 h[8]; uint4 u; } r;
    r.h[0] = __float2bfloat16(a.x); r.h[1] = __float2bfloat16(a.y);
    r.h[2] = __float2bfloat16(a.z); r.h[3] = __float2bfloat16(a.w);
    r.h[4] = __float2bfloat16(b.x); r.h[5] = __float2bfloat16(b.y);
    r.h[6] = __float2bfloat16(b.z); r.h[7] = __float2bfloat16(b.w);
    *(uint4*)(out + i) = r.u;
}

// ---------------------------------------------------------------------------
// LayerNorm over rows of 256: one 64-lane wave per row. OT = float or bf16.
// ---------------------------------------------------------------------------
template<typename OT>
__global__ __launch_bounds__(64)
void ln_kernel(const float* __restrict__ in, const float* __restrict__ g,
               const float* __restrict__ b, OT* __restrict__ out)
{
    const int row = blockIdx.x;
    const int t = threadIdx.x;
    const float* x = in + (size_t)row * DM;

    float v[4];
    float s = 0.f;
    #pragma unroll
    for (int j = 0; j < 4; ++j) { v[j] = x[t + 64 * j]; s += v[j]; }
    #pragma unroll
    for (int m = 1; m < 64; m <<= 1) s += __shfl_xor(s, m, 64);
    const float mu = s * (1.f / DM);

    float s2 = 0.f;
    #pragma unroll
    for (int j = 0; j < 4; ++j) { float d = v[j] - mu; s2 += d * d; }
    #pragma unroll
    for (int m = 1; m < 64; m <<= 1) s2 += __shfl_xor(s2, m, 64);
    const float var = s2 * (1.f / DM);
    const float sc = 1.f / sqrtf(var + 1e-5f);

    #pragma unroll
    for (int j = 0; j < 4; ++j) {
        const int c = t + 64 * j;
        out[(size_t)row * DM + c] = (OT)((v[j] - mu) * sc * g[c] + b[c]);
    }
}

// ---------------------------------------------------------------------------
// Causal depthwise conv (width 4) + SiLU.
// ---------------------------------------------------------------------------
__global__ __launch_bounds__(256)
void conv_silu_kernel(const float* __restrict__ xz, const float* __restrict__ cw,
                      const float* __restrict__ cb, float* __restrict__ xc)
{
    const int idx = blockIdx.x * 256 + threadIdx.x;
    const int d = idx & (DI - 1);
    const int m = idx >> 9;
    const int l = m & (LSEQ - 1);

    float acc = cb[d];
    #pragma unroll
    for (int k = 0; k < 4; ++k) {
        const int ll = l + k - 3;
        if (ll >= 0)
            acc += xz[(size_t)(m + k - 3) * 1024 + d] * cw[d * 4 + k];
    }
    const float sg = 1.f / (1.f + __expf(-acc));
    xc[idx] = acc * sg;
}

// ---------------------------------------------------------------------------
// Chunked parallel selective scan (3 passes). part3 writes bf16 gated output.
// ---------------------------------------------------------------------------
__global__ __launch_bounds__(256)
void scan_part1(const float* __restrict__ delta, const float* __restrict__ xc,
                const float* __restrict__ dbc, const float* __restrict__ A_log,
                float* __restrict__ S, float* __restrict__ Dsum)
{
    const int blk = blockIdx.x;
    const int bc  = blk >> 1;
    const int d   = ((blk & 1) << 8) + threadIdx.x;
    const int b   = bc >> 5;
    const int c   = bc & (NC - 1);

    float a[16], h[16];
    #pragma unroll
    for (int n = 0; n < 16; ++n) {
        a[n] = -__expf(A_log[d * 16 + n]);
        h[n] = 0.f;
    }
    float dsum = 0.f;

    const int m0 = b * LSEQ + c * CT;
    for (int t = 0; t < CT; ++t) {
        const size_t m = (size_t)(m0 + t);
        const float dt = delta[m * DI + d];
        const float u  = xc[m * DI + d];
        const float du = dt * u;
        dsum += dt;
        const float* Bp = dbc + m * 48 + DTR;
        #pragma unroll
        for (int n = 0; n < 16; ++n)
            h[n] = h[n] * __expf(dt * a[n]) + du * Bp[n];
    }
    float* Sp = S + ((size_t)bc * DI + d) * 16;
    #pragma unroll
    for (int n = 0; n < 16; ++n) Sp[n] = h[n];
    Dsum[(size_t)bc * DI + d] = dsum;
}

__global__ __launch_bounds__(256)
void scan_part2(const float* __restrict__ A_log, const float* __restrict__ Dsum,
                float* __restrict__ S)
{
    const int gid = blockIdx.x * 256 + threadIdx.x;
    const int n = gid & 15;
    const int d = (gid >> 4) & (DI - 1);
    const int b = gid >> 13;

    const float a = -__expf(A_log[d * 16 + n]);
    float h = 0.f;
    for (int c = 0; c < NC; ++c) {
        const size_t bcd = (size_t)(b * NC + c) * DI + d;
        const size_t idx = bcd * 16 + n;
        const float s = S[idx];
        S[idx] = h;
        h = __expf(a * Dsum[bcd]) * h + s;
    }
}

__global__ __launch_bounds__(256)
void scan_part3(const float* __restrict__ delta, const float* __restrict__ xc,
                const float* __restrict__ dbc, const float* __restrict__ xz,
                const float* __restrict__ A_log, const float* __restrict__ Dp,
                const float* __restrict__ H, __hip_bfloat16* __restrict__ yg)
{
    const int blk = blockIdx.x;
    const int bc  = blk >> 1;
    const int d   = ((blk & 1) << 8) + threadIdx.x;
    const int b   = bc >> 5;
    const int c   = bc & (NC - 1);

    float a[16], h[16];
    const float* Hp = H + ((size_t)bc * DI + d) * 16;
    #pragma unroll
    for (int n = 0; n < 16; ++n) {
        a[n] = -__expf(A_log[d * 16 + n]);
        h[n] = Hp[n];
    }
    const float Dv = Dp[d];

    const int m0 = b * LSEQ + c * CT;
    for (int t = 0; t < CT; ++t) {
        const size_t m = (size_t)(m0 + t);
        const float dt = delta[m * DI + d];
        const float u  = xc[m * DI + d];
        const float du = dt * u;
        const float* Bp = dbc + m * 48 + DTR;
        const float* Cp = Bp + DS;
        float y = 0.f;
        #pragma unroll
        for (int n = 0; n < 16; ++n) {
            h[n] = h[n] * __expf(dt * a[n]) + du * Bp[n];
            y += h[n] * Cp[n];
        }
        const float z = xz[m * 1024 + DI + d];
        const float g = z / (1.f + __expf(-z));
        yg[m * DI + d] = __float2bfloat16((y + u * Dv) * g);
    }
}

// ---------------------------------------------------------------------------
extern "C" void kernel_launch(void* const* d_in, const int* in_sizes, int n_in,
                              void* d_out, int out_size, void* d_ws, size_t ws_size,
                              hipStream_t stream) {
    const float* x          = (const float*)d_in[0];
    const float* proj_in_w  = (const float*)d_in[1];
    const float* proj_in_b  = (const float*)d_in[2];
    const float* ln_gamma   = (const float*)d_in[3];
    const float* ln_beta    = (const float*)d_in[4];
    const float* in_proj_w  = (const float*)d_in[5];
    const float* conv_w     = (const float*)d_in[6];
    const float* conv_b     = (const float*)d_in[7];
    const float* x_proj_w   = (const float*)d_in[8];
    const float* dt_proj_w  = (const float*)d_in[9];
    const float* dt_proj_b  = (const float*)d_in[10];
    const float* A_log      = (const float*)d_in[11];
    const float* Dvec       = (const float*)d_in[12];
    const float* out_proj_w = (const float*)d_in[13];
    const float* res_scale  = (const float*)d_in[14];
    const float* out_gamma  = (const float*)d_in[15];
    const float* out_beta   = (const float*)d_in[16];

    float* ws     = (float*)d_ws;
    float* h_buf  = ws;                                    // 2097152 f
    float* xz     = h_buf + 2097152;                       // 8388608 f
    float* xc     = xz    + 8388608;                       // 4194304 f
    float* delta  = xc    + 4194304;                       // 4194304 f
    float* dbc    = delta + 4194304;                       // 393216 f
    float* Sbuf   = dbc   + 393216;                        // 2097152 f
    float* Dsum   = Sbuf  + 2097152;                       // 131072 f
    __hip_bfloat16* ln_bf = (__hip_bfloat16*)(Dsum + 131072);          // 2M elems
    __hip_bfloat16* yg_bf = (__hip_bfloat16*)(Dsum + 131072 + 1048576); // 4M elems
    __hip_bfloat16* w_in_bf  = (__hip_bfloat16*)(Dsum + 131072 + 1048576 + 2097152); // 1M
    __hip_bfloat16* w_out_bf = w_in_bf + 4 * 1024 * 256;   // 0.5M elems

    // One-time (per launch) weight conversions to bf16.
    cvt_bf16_kernel<<<(4 * 1024 * 256 / 8 + 255) / 256, 256, 0, stream>>>(
        in_proj_w, w_in_bf, 4 * 1024 * 256);
    cvt_bf16_kernel<<<(4 * 256 * 512 / 8 + 255) / 256, 256, 0, stream>>>(
        out_proj_w, w_out_bf, 4 * 256 * 512);

    // h = x @ proj_in_w^T + proj_in_b  (fp32, K=80)
    gemm_nt<0, false><<<dim3(128, 4), 256, 0, stream>>>(
        x, 80, proj_in_w, proj_in_b, nullptr, h_buf, DM, M_ROWS, DM, 80);

    for (int i = 0; i < 4; ++i) {
        const __hip_bfloat16* in_w = w_in_bf + (size_t)i * 2 * DI * DM;
        const __hip_bfloat16* ow   = w_out_bf + (size_t)i * DM * DI;
        const float* cw    = conv_w     + (size_t)i * DI * 4;
        const float* cb    = conv_b     + (size_t)i * DI;
        const float* xw    = x_proj_w   + (size_t)i * 48 * DI;
        const float* dtw   = dt_proj_w  + (size_t)i * DI * DTR;
        const float* dtb   = dt_proj_b  + (size_t)i * DI;
        const float* Al    = A_log      + (size_t)i * DI * DS;
        const float* Dl    = Dvec       + (size_t)i * DI;

        ln_kernel<__hip_bfloat16><<<M_ROWS, 64, 0, stream>>>(
            h_buf, ln_gamma + i * DM, ln_beta + i * DM, ln_bf);
        // xz = ln @ in_w^T  (bf16 MFMA, M=8192 N=1024 K=256)
        gemm_bt_mfma<false><<<dim3(64, 16), 256, 0, stream>>>(
            ln_bf, in_w, nullptr, xz, M_ROWS, 1024, DM);
        conv_silu_kernel<<<(M_ROWS * DI) / 256, 256, 0, stream>>>(xz, cw, cb, xc);
        // dbc = xc @ xw^T  (fp32, N=48 K=512)
        gemm_nt<0, false><<<dim3(128, 1), 256, 0, stream>>>(
            xc, DI, xw, nullptr, nullptr, dbc, 48, M_ROWS, 48, DI);
        // delta = softplus(dbc[:, :16] @ dtw^T + dtb)  (fp32, K=16)
        gemm_nt<1, false><<<dim3(128, 8), 256, 0, stream>>>(
            dbc, 48, dtw, dtb, nullptr, delta, DI, M_ROWS, DI, DTR);

        scan_part1<<<8 * NC * 2, 256, 0, stream>>>(delta, xc, dbc, Al, Sbuf, Dsum);
        scan_part2<<<(8 * DI * 16) / 256, 256, 0, stream>>>(Al, Dsum, Sbuf);
        scan_part3<<<8 * NC * 2, 256, 0, stream>>>(delta, xc, dbc, xz, Al, Dl,
                                                   Sbuf, yg_bf);

        // h += res_scale * (yg @ ow^T)  (bf16 MFMA, M=8192 N=256 K=512)
        gemm_bt_mfma<true><<<dim3(64, 4), 256, 0, stream>>>(
            yg_bf, ow, res_scale, h_buf, M_ROWS, DM, DI);
    }

    ln_kernel<float><<<M_ROWS, 64, 0, stream>>>(h_buf, out_gamma, out_beta,
                                                (float*)d_out);
}

// Round 4
// 646.647 us; speedup vs baseline: 5.1201x; 1.1207x over previous
//
#include <hip/hip_runtime.h>
#include <hip/hip_bf16.h>

#define M_ROWS 8192      // B*L
#define DM 256           // D_MODEL
#define DI 512           // D_INNER
#define DS 16            // D_STATE
#define DTR 16           // DT_RANK
#define LSEQ 1024
#define NC 32            // chunks per sequence
#define CT 32            // chunk length

typedef __bf16 bf16x8 __attribute__((ext_vector_type(8)));
typedef float  f32x4  __attribute__((ext_vector_type(4)));

__device__ __forceinline__ bf16x8 ld8(const __hip_bfloat16* p) {
    uint4 u = *(const uint4*)p;
    return __builtin_bit_cast(bf16x8, u);
}

// ---------------------------------------------------------------------------
// bf16 MFMA GEMM:  C[m,n] (+)= alpha * (sum_k A[m,k] * W[n,k] + bias[n])
// A: M x K bf16 row-major.  W: N x K bf16 row-major.  C: M x N fp32.
// Block: 256 thr = 4 waves stacked in M; per-wave 32(M) x 64(N); block 128x64.
// ---------------------------------------------------------------------------
template<bool ACCUM>
__global__ __launch_bounds__(256)
void gemm_bt_mfma(const __hip_bfloat16* __restrict__ A,
                  const __hip_bfloat16* __restrict__ W,
                  const float* __restrict__ bias,
                  const float* __restrict__ alpha_p,
                  float* __restrict__ C,
                  int M, int N, int K)
{
    const int w  = threadIdx.x >> 6;
    const int l  = threadIdx.x & 63;
    const int lr = l & 15;
    const int kb = l >> 4;
    const int m0 = blockIdx.x * 128 + w * 32;
    const int n0 = blockIdx.y * 64;

    f32x4 acc[2][4];
    #pragma unroll
    for (int mi = 0; mi < 2; ++mi)
        #pragma unroll
        for (int ni = 0; ni < 4; ++ni)
            acc[mi][ni] = (f32x4){0.f, 0.f, 0.f, 0.f};

    const __hip_bfloat16* pA = A + (size_t)(m0 + lr) * K + kb * 8;
    const __hip_bfloat16* pW = W + (size_t)(n0 + lr) * K + kb * 8;
    const size_t sK16 = (size_t)16 * K;

    #pragma unroll 2
    for (int k0 = 0; k0 < K; k0 += 32) {
        bf16x8 a0 = ld8(pA + k0);
        bf16x8 a1 = ld8(pA + sK16 + k0);
        bf16x8 b0 = ld8(pW + k0);
        bf16x8 b1 = ld8(pW + sK16 + k0);
        bf16x8 b2 = ld8(pW + 2 * sK16 + k0);
        bf16x8 b3 = ld8(pW + 3 * sK16 + k0);

        acc[0][0] = __builtin_amdgcn_mfma_f32_16x16x32_bf16(a0, b0, acc[0][0], 0, 0, 0);
        acc[1][0] = __builtin_amdgcn_mfma_f32_16x16x32_bf16(a1, b0, acc[1][0], 0, 0, 0);
        acc[0][1] = __builtin_amdgcn_mfma_f32_16x16x32_bf16(a0, b1, acc[0][1], 0, 0, 0);
        acc[1][1] = __builtin_amdgcn_mfma_f32_16x16x32_bf16(a1, b1, acc[1][1], 0, 0, 0);
        acc[0][2] = __builtin_amdgcn_mfma_f32_16x16x32_bf16(a0, b2, acc[0][2], 0, 0, 0);
        acc[1][2] = __builtin_amdgcn_mfma_f32_16x16x32_bf16(a1, b2, acc[1][2], 0, 0, 0);
        acc[0][3] = __builtin_amdgcn_mfma_f32_16x16x32_bf16(a0, b3, acc[0][3], 0, 0, 0);
        acc[1][3] = __builtin_amdgcn_mfma_f32_16x16x32_bf16(a1, b3, acc[1][3], 0, 0, 0);
    }

    const float alpha = alpha_p ? alpha_p[0] : 1.0f;
    #pragma unroll
    for (int mi = 0; mi < 2; ++mi) {
        #pragma unroll
        for (int ni = 0; ni < 4; ++ni) {
            const int col = n0 + ni * 16 + lr;
            const float bv = bias ? bias[col] : 0.f;
            #pragma unroll
            for (int r = 0; r < 4; ++r) {
                const int row = m0 + mi * 16 + kb * 4 + r;
                const size_t idx = (size_t)row * N + col;
                const float v = acc[mi][ni][r] + bv;
                if (ACCUM) C[idx] += alpha * v;
                else       C[idx] = v;
            }
        }
    }
}

// ---------------------------------------------------------------------------
// Fused x_proj+dt_proj GEMM: A(8192x512 bf16) @ Wc(544x512 bf16)^T.
// cols 0..511  -> delta = softplus(acc + dtb[col])
// cols 512..543-> bc[row][col-512]  (B then C, fp32)
// ---------------------------------------------------------------------------
__global__ __launch_bounds__(256)
void gemm_dt_bc(const __hip_bfloat16* __restrict__ A,
                const __hip_bfloat16* __restrict__ Wc,
                const float* __restrict__ dtb,
                float* __restrict__ delta,
                float* __restrict__ bc)
{
    const int K = 512;
    const int w  = threadIdx.x >> 6;
    const int l  = threadIdx.x & 63;
    const int lr = l & 15;
    const int kb = l >> 4;
    const int m0 = blockIdx.x * 128 + w * 32;
    const int n0 = blockIdx.y * 64;

    f32x4 acc[2][4];
    #pragma unroll
    for (int mi = 0; mi < 2; ++mi)
        #pragma unroll
        for (int ni = 0; ni < 4; ++ni)
            acc[mi][ni] = (f32x4){0.f, 0.f, 0.f, 0.f};

    const int r0 = min(n0 + lr,      543);
    const int r1 = min(n0 + lr + 16, 543);
    const int r2 = min(n0 + lr + 32, 543);
    const int r3 = min(n0 + lr + 48, 543);
    const __hip_bfloat16* pA  = A  + (size_t)(m0 + lr) * K + kb * 8;
    const __hip_bfloat16* pW0 = Wc + (size_t)r0 * K + kb * 8;
    const __hip_bfloat16* pW1 = Wc + (size_t)r1 * K + kb * 8;
    const __hip_bfloat16* pW2 = Wc + (size_t)r2 * K + kb * 8;
    const __hip_bfloat16* pW3 = Wc + (size_t)r3 * K + kb * 8;
    const size_t sK16 = (size_t)16 * K;

    #pragma unroll 2
    for (int k0 = 0; k0 < K; k0 += 32) {
        bf16x8 a0 = ld8(pA + k0);
        bf16x8 a1 = ld8(pA + sK16 + k0);
        bf16x8 b0 = ld8(pW0 + k0);
        bf16x8 b1 = ld8(pW1 + k0);
        bf16x8 b2 = ld8(pW2 + k0);
        bf16x8 b3 = ld8(pW3 + k0);

        acc[0][0] = __builtin_amdgcn_mfma_f32_16x16x32_bf16(a0, b0, acc[0][0], 0, 0, 0);
        acc[1][0] = __builtin_amdgcn_mfma_f32_16x16x32_bf16(a1, b0, acc[1][0], 0, 0, 0);
        acc[0][1] = __builtin_amdgcn_mfma_f32_16x16x32_bf16(a0, b1, acc[0][1], 0, 0, 0);
        acc[1][1] = __builtin_amdgcn_mfma_f32_16x16x32_bf16(a1, b1, acc[1][1], 0, 0, 0);
        acc[0][2] = __builtin_amdgcn_mfma_f32_16x16x32_bf16(a0, b2, acc[0][2], 0, 0, 0);
        acc[1][2] = __builtin_amdgcn_mfma_f32_16x16x32_bf16(a1, b2, acc[1][2], 0, 0, 0);
        acc[0][3] = __builtin_amdgcn_mfma_f32_16x16x32_bf16(a0, b3, acc[0][3], 0, 0, 0);
        acc[1][3] = __builtin_amdgcn_mfma_f32_16x16x32_bf16(a1, b3, acc[1][3], 0, 0, 0);
    }

    #pragma unroll
    for (int mi = 0; mi < 2; ++mi) {
        #pragma unroll
        for (int ni = 0; ni < 4; ++ni) {
            const int col = n0 + ni * 16 + lr;
            #pragma unroll
            for (int r = 0; r < 4; ++r) {
                const int row = m0 + mi * 16 + kb * 4 + r;
                float v = acc[mi][ni][r];
                if (col < 512) {
                    v += dtb[col];
                    v = (v > 20.f) ? v : log1pf(__expf(v));
                    delta[(size_t)row * DI + col] = v;
                } else if (col < 544) {
                    bc[(size_t)row * 32 + (col - 512)] = v;
                }
            }
        }
    }
}

// ---------------------------------------------------------------------------
// Build W_comb (per layer, 544x512 bf16): rows 0..511 = dtw @ xw[0:16];
// rows 512..543 = xw[16:48].
// ---------------------------------------------------------------------------
__global__ __launch_bounds__(256)
void prep_wcomb(const float* __restrict__ xw, const float* __restrict__ dtw,
                __hip_bfloat16* __restrict__ Wc)
{
    const int idx = blockIdx.x * 256 + threadIdx.x;   // 4*544*512
    const int lyr = idx / (544 * 512);
    const int rem = idx - lyr * (544 * 512);
    const int n = rem >> 9;
    const int k = rem & 511;

    const float* xwl  = xw  + (size_t)lyr * 48 * 512;
    float s;
    if (n < 512) {
        const float* dtn = dtw + (size_t)lyr * 512 * 16 + n * 16;
        s = 0.f;
        #pragma unroll
        for (int r = 0; r < 16; ++r) s += dtn[r] * xwl[r * 512 + k];
    } else {
        s = xwl[(16 + n - 512) * 512 + k];
    }
    Wc[idx] = __float2bfloat16(s);
}

// ---------------------------------------------------------------------------
// fp32 -> bf16 conversion (8 elems/thread).
// ---------------------------------------------------------------------------
__global__ __launch_bounds__(256)
void cvt_bf16_kernel(const float* __restrict__ in, __hip_bfloat16* __restrict__ out,
                     int n)
{
    const int i = (blockIdx.x * 256 + threadIdx.x) * 8;
    if (i >= n) return;
    float4 a = *(const float4*)(in + i);
    float4 b = *(const float4*)(in + i + 4);
    union { __hip_bfloat16 h[8]; uint4 u; } r;
    r.h[0] = __float2bfloat16(a.x); r.h[1] = __float2bfloat16(a.y);
    r.h[2] = __float2bfloat16(a.z); r.h[3] = __float2bfloat16(a.w);
    r.h[4] = __float2bfloat16(b.x); r.h[5] = __float2bfloat16(b.y);
    r.h[6] = __float2bfloat16(b.z); r.h[7] = __float2bfloat16(b.w);
    *(uint4*)(out + i) = r.u;
}

// fp32 -> bf16 with row padding (incols -> outcols, zero fill).
__global__ __launch_bounds__(256)
void cvt_pad_bf16(const float* __restrict__ in, __hip_bfloat16* __restrict__ out,
                  int rows, int incols, int outcols)
{
    const int idx = blockIdx.x * 256 + threadIdx.x;
    if (idx >= rows * outcols) return;
    const int r = idx / outcols;
    const int c = idx - r * outcols;
    out[idx] = __float2bfloat16(c < incols ? in[(size_t)r * incols + c] : 0.f);
}

// ---------------------------------------------------------------------------
// LayerNorm over rows of 256: one 64-lane wave per row.
// ---------------------------------------------------------------------------
template<typename OT>
__global__ __launch_bounds__(64)
void ln_kernel(const float* __restrict__ in, const float* __restrict__ g,
               const float* __restrict__ b, OT* __restrict__ out)
{
    const int row = blockIdx.x;
    const int t = threadIdx.x;
    const float* x = in + (size_t)row * DM;

    float v[4];
    float s = 0.f;
    #pragma unroll
    for (int j = 0; j < 4; ++j) { v[j] = x[t + 64 * j]; s += v[j]; }
    #pragma unroll
    for (int m = 1; m < 64; m <<= 1) s += __shfl_xor(s, m, 64);
    const float mu = s * (1.f / DM);

    float s2 = 0.f;
    #pragma unroll
    for (int j = 0; j < 4; ++j) { float d = v[j] - mu; s2 += d * d; }
    #pragma unroll
    for (int m = 1; m < 64; m <<= 1) s2 += __shfl_xor(s2, m, 64);
    const float var = s2 * (1.f / DM);
    const float sc = 1.f / sqrtf(var + 1e-5f);

    #pragma unroll
    for (int j = 0; j < 4; ++j) {
        const int c = t + 64 * j;
        out[(size_t)row * DM + c] = (OT)((v[j] - mu) * sc * g[c] + b[c]);
    }
}

// ---------------------------------------------------------------------------
// Rolling causal conv4 + SiLU. 8 timesteps per thread; each input read once.
// Writes xc fp32 (scan) and bf16 (GEMM A operand).
// ---------------------------------------------------------------------------
__global__ __launch_bounds__(256)
void conv_silu2(const float* __restrict__ xz, const float* __restrict__ cw,
                const float* __restrict__ cb, float* __restrict__ xc,
                __hip_bfloat16* __restrict__ xcb)
{
    const int idx = blockIdx.x * 256 + threadIdx.x;   // 8192*512/8
    const int d = idx & (DI - 1);
    const int g = idx >> 9;           // 0..1023
    const int b = g >> 7;
    const int l0 = (g & 127) * 8;

    const float w0 = cw[d * 4 + 0], w1 = cw[d * 4 + 1];
    const float w2 = cw[d * 4 + 2], w3 = cw[d * 4 + 3];
    const float bias = cb[d];

    const size_t base = ((size_t)b << 10);
    float xm3 = (l0 >= 3) ? xz[(base + l0 - 3) * 1024 + d] : 0.f;
    float xm2 = (l0 >= 2) ? xz[(base + l0 - 2) * 1024 + d] : 0.f;
    float xm1 = (l0 >= 1) ? xz[(base + l0 - 1) * 1024 + d] : 0.f;

    #pragma unroll
    for (int j = 0; j < 8; ++j) {
        const size_t m = base + l0 + j;
        const float xc0 = xz[m * 1024 + d];
        float acc = bias + w0 * xm3 + w1 * xm2 + w2 * xm1 + w3 * xc0;
        const float sg = 1.f / (1.f + __expf(-acc));
        const float v = acc * sg;
        xc[m * DI + d]  = v;
        xcb[m * DI + d] = __float2bfloat16(v);
        xm3 = xm2; xm2 = xm1; xm1 = xc0;
    }
}

// ---------------------------------------------------------------------------
// Chunked parallel selective scan (3 passes), bc is 32-wide [B(16)|C(16)].
// ---------------------------------------------------------------------------
__global__ __launch_bounds__(256)
void scan_part1(const float* __restrict__ delta, const float* __restrict__ xc,
                const float* __restrict__ bc, const float* __restrict__ A_log,
                float* __restrict__ S, float* __restrict__ Dsum)
{
    const int blk = blockIdx.x;
    const int bcx = blk >> 1;
    const int d   = ((blk & 1) << 8) + threadIdx.x;
    const int b   = bcx >> 5;
    const int c   = bcx & (NC - 1);

    float a[16], h[16];
    #pragma unroll
    for (int n = 0; n < 16; ++n) {
        a[n] = -__expf(A_log[d * 16 + n]);
        h[n] = 0.f;
    }
    float dsum = 0.f;

    const int m0 = b * LSEQ + c * CT;
    for (int t = 0; t < CT; ++t) {
        const size_t m = (size_t)(m0 + t);
        const float dt = delta[m * DI + d];
        const float u  = xc[m * DI + d];
        const float du = dt * u;
        dsum += dt;
        const float* Bp = bc + m * 32;
        #pragma unroll
        for (int n = 0; n < 16; ++n)
            h[n] = h[n] * __expf(dt * a[n]) + du * Bp[n];
    }
    float* Sp = S + ((size_t)bcx * DI + d) * 16;
    #pragma unroll
    for (int n = 0; n < 16; ++n) Sp[n] = h[n];
    Dsum[(size_t)bcx * DI + d] = dsum;
}

__global__ __launch_bounds__(256)
void scan_part2(const float* __restrict__ A_log, const float* __restrict__ Dsum,
                float* __restrict__ S)
{
    const int gid = blockIdx.x * 256 + threadIdx.x;
    const int n = gid & 15;
    const int d = (gid >> 4) & (DI - 1);
    const int b = gid >> 13;

    const float a = -__expf(A_log[d * 16 + n]);
    float h = 0.f;
    for (int c = 0; c < NC; ++c) {
        const size_t bcd = (size_t)(b * NC + c) * DI + d;
        const size_t idx = bcd * 16 + n;
        const float s = S[idx];
        S[idx] = h;
        h = __expf(a * Dsum[bcd]) * h + s;
    }
}

__global__ __launch_bounds__(256)
void scan_part3(const float* __restrict__ delta, const float* __restrict__ xc,
                const float* __restrict__ bc, const float* __restrict__ xz,
                const float* __restrict__ A_log, const float* __restrict__ Dp,
                const float* __restrict__ H, __hip_bfloat16* __restrict__ yg)
{
    const int blk = blockIdx.x;
    const int bcx = blk >> 1;
    const int d   = ((blk & 1) << 8) + threadIdx.x;
    const int b   = bcx >> 5;
    const int c   = bcx & (NC - 1);

    float a[16], h[16];
    const float* Hp = H + ((size_t)bcx * DI + d) * 16;
    #pragma unroll
    for (int n = 0; n < 16; ++n) {
        a[n] = -__expf(A_log[d * 16 + n]);
        h[n] = Hp[n];
    }
    const float Dv = Dp[d];

    const int m0 = b * LSEQ + c * CT;
    for (int t = 0; t < CT; ++t) {
        const size_t m = (size_t)(m0 + t);
        const float dt = delta[m * DI + d];
        const float u  = xc[m * DI + d];
        const float du = dt * u;
        const float* Bp = bc + m * 32;
        const float* Cp = Bp + 16;
        float y = 0.f;
        #pragma unroll
        for (int n = 0; n < 16; ++n) {
            h[n] = h[n] * __expf(dt * a[n]) + du * Bp[n];
            y += h[n] * Cp[n];
        }
        const float z = xz[m * 1024 + DI + d];
        const float gt = z / (1.f + __expf(-z));
        yg[m * DI + d] = __float2bfloat16((y + u * Dv) * gt);
    }
}

// ---------------------------------------------------------------------------
extern "C" void kernel_launch(void* const* d_in, const int* in_sizes, int n_in,
                              void* d_out, int out_size, void* d_ws, size_t ws_size,
                              hipStream_t stream) {
    const float* x          = (const float*)d_in[0];
    const float* proj_in_w  = (const float*)d_in[1];
    const float* proj_in_b  = (const float*)d_in[2];
    const float* ln_gamma   = (const float*)d_in[3];
    const float* ln_beta    = (const float*)d_in[4];
    const float* in_proj_w  = (const float*)d_in[5];
    const float* conv_w     = (const float*)d_in[6];
    const float* conv_b     = (const float*)d_in[7];
    const float* x_proj_w   = (const float*)d_in[8];
    const float* dt_proj_w  = (const float*)d_in[9];
    const float* dt_proj_b  = (const float*)d_in[10];
    const float* A_log      = (const float*)d_in[11];
    const float* Dvec       = (const float*)d_in[12];
    const float* out_proj_w = (const float*)d_in[13];
    const float* res_scale  = (const float*)d_in[14];
    const float* out_gamma  = (const float*)d_in[15];
    const float* out_beta   = (const float*)d_in[16];

    float* ws     = (float*)d_ws;
    float* h_buf  = ws;                     // 2097152
    float* xz     = h_buf + 2097152;        // 8388608
    float* xc     = xz    + 8388608;        // 4194304
    float* delta  = xc    + 4194304;        // 4194304
    float* bc     = delta + 4194304;        // 262144
    float* Sbuf   = bc    + 262144;         // 2097152
    float* Dsum   = Sbuf  + 2097152;        // 131072
    float* fend   = Dsum  + 131072;
    __hip_bfloat16* ln_bf    = (__hip_bfloat16*)fend;              // 2M elems
    __hip_bfloat16* yg_bf    = ln_bf    + 2097152;                 // 4M elems
    __hip_bfloat16* xcb      = yg_bf    + 4194304;                 // 4M elems
    __hip_bfloat16* w_in_bf  = xcb      + 4194304;                 // 1M elems
    __hip_bfloat16* w_out_bf = w_in_bf  + 4 * 1024 * 256;          // 0.5M elems
    __hip_bfloat16* Wc       = w_out_bf + 4 * 256 * 512;           // 4*544*512
    __hip_bfloat16* x_pad    = Wc       + 4 * 544 * 512;           // 8192*96
    __hip_bfloat16* w_pi     = x_pad    + 8192 * 96;               // 256*96

    // ---- one-time weight prep ----
    cvt_bf16_kernel<<<(4 * 1024 * 256 / 8 + 255) / 256, 256, 0, stream>>>(
        in_proj_w, w_in_bf, 4 * 1024 * 256);
    cvt_bf16_kernel<<<(4 * 256 * 512 / 8 + 255) / 256, 256, 0, stream>>>(
        out_proj_w, w_out_bf, 4 * 256 * 512);
    prep_wcomb<<<(4 * 544 * 512) / 256, 256, 0, stream>>>(x_proj_w, dt_proj_w, Wc);
    cvt_pad_bf16<<<(8192 * 96 + 255) / 256, 256, 0, stream>>>(x, x_pad, 8192, 80, 96);
    cvt_pad_bf16<<<(256 * 96 + 255) / 256, 256, 0, stream>>>(proj_in_w, w_pi, 256, 80, 96);

    // h = x @ proj_in_w^T + b  (bf16 MFMA, K padded to 96)
    gemm_bt_mfma<false><<<dim3(64, 4), 256, 0, stream>>>(
        x_pad, w_pi, proj_in_b, nullptr, h_buf, M_ROWS, DM, 96);

    for (int i = 0; i < 4; ++i) {
        const __hip_bfloat16* in_w = w_in_bf + (size_t)i * 1024 * 256;
        const __hip_bfloat16* ow   = w_out_bf + (size_t)i * 256 * 512;
        const __hip_bfloat16* Wci  = Wc + (size_t)i * 544 * 512;
        const float* cw  = conv_w    + (size_t)i * DI * 4;
        const float* cb  = conv_b    + (size_t)i * DI;
        const float* dtb = dt_proj_b + (size_t)i * DI;
        const float* Al  = A_log     + (size_t)i * DI * DS;
        const float* Dl  = Dvec      + (size_t)i * DI;

        ln_kernel<__hip_bfloat16><<<M_ROWS, 64, 0, stream>>>(
            h_buf, ln_gamma + i * DM, ln_beta + i * DM, ln_bf);
        gemm_bt_mfma<false><<<dim3(64, 16), 256, 0, stream>>>(
            ln_bf, in_w, nullptr, nullptr, xz, M_ROWS, 1024, DM);
        conv_silu2<<<(M_ROWS * DI / 8) / 256, 256, 0, stream>>>(xz, cw, cb, xc, xcb);
        gemm_dt_bc<<<dim3(64, 9), 256, 0, stream>>>(xcb, Wci, dtb, delta, bc);

        scan_part1<<<8 * NC * 2, 256, 0, stream>>>(delta, xc, bc, Al, Sbuf, Dsum);
        scan_part2<<<(8 * DI * 16) / 256, 256, 0, stream>>>(Al, Dsum, Sbuf);
        scan_part3<<<8 * NC * 2, 256, 0, stream>>>(delta, xc, bc, xz, Al, Dl,
                                                   Sbuf, yg_bf);

        gemm_bt_mfma<true><<<dim3(64, 4), 256, 0, stream>>>(
            yg_bf, ow, nullptr, res_scale, h_buf, M_ROWS, DM, DI);
    }

    ln_kernel<float><<<M_ROWS, 64, 0, stream>>>(h_buf, out_gamma, out_beta,
                                                (float*)d_out);
}